// Round 13
// baseline (265.682 us; speedup 1.0000x reference)
//
#include <hip/hip_runtime.h>
#include <stdint.h>

typedef __attribute__((ext_vector_type(8))) short bf16x8;   // 8 bf16 = 4 VGPRs (MFMA operand)
typedef __attribute__((ext_vector_type(4))) float f32x4;    // MFMA acc
typedef __attribute__((ext_vector_type(4))) float float4v;
typedef __attribute__((ext_vector_type(4))) unsigned int u32x4;  // native 16B vector

#define F 256
#define NCHUNK 8                  // feature chunks == XCD count
#define CW 32                     // chunk width; N*CW*2B = 3.2MB <= 4MB per-XCD L2
#define BKT_SHIFT 7               // 128 nodes per bucket
#define BKT_NODES 128
#define MAXNB 512                 // N <= 65536
#define CAP 6144                  // fixed bucket capacity (mean 4092+pad<=896; +32sigma safe)
#define CHUNK 4096                // edges per block in scatter

static __device__ __forceinline__ float asf(uint32_t u) {
  union { uint32_t u; float f; } x; x.u = u; return x.f;
}
static __device__ __forceinline__ unsigned short f2bf(float f) {
  union { float f; uint32_t u; } x; x.f = f;
  uint32_t u = x.u;
  return (unsigned short)((u + 0x7FFFu + ((u >> 16) & 1u)) >> 16);  // RNE, matches np/jax cast
}

// ---- scatter edges into fixed-capacity bucket regions: pairs[b*CAP + pos] = src | dstlocal<<16
__global__ __launch_bounds__(256) void scatter_kernel(const int* __restrict__ src,
                                                      const int* __restrict__ dst,
                                                      int* __restrict__ gcursor,
                                                      uint32_t* __restrict__ pairs, int E, int NB) {
  __shared__ int cnt[MAXNB];
  __shared__ int gbase[MAXNB];
  const int tid = threadIdx.x;
  for (int t = tid; t < MAXNB; t += 256) cnt[t] = 0;
  __syncthreads();
  const int base = blockIdx.x * CHUNK;
  uint32_t val[16];
  int bk[16], pos[16];
  if (base + CHUNK <= E) {                 // fast path: full chunk, vector loads
    const int i0 = base + tid * 16;
#pragma unroll
    for (int q = 0; q < 4; ++q) {
      const u32x4 s0 = *reinterpret_cast<const u32x4*>(src + i0 + q * 4);
      const u32x4 d0 = *reinterpret_cast<const u32x4*>(dst + i0 + q * 4);
      uint32_t sv[4] = {s0.x, s0.y, s0.z, s0.w};
      uint32_t dv[4] = {d0.x, d0.y, d0.z, d0.w};
#pragma unroll
      for (int j = 0; j < 4; ++j) {
        int jj = q * 4 + j;
        bk[jj] = (int)(dv[j] >> BKT_SHIFT);
        val[jj] = sv[j] | ((dv[j] & (BKT_NODES - 1)) << 16);
        pos[jj] = atomicAdd(&cnt[bk[jj]], 1);
      }
    }
  } else {                                  // tail block: guarded scalar
#pragma unroll
    for (int j = 0; j < 16; ++j) {
      int i = base + tid * 16 + j;
      if (i < E) {
        uint32_t s = (uint32_t)src[i], d = (uint32_t)dst[i];
        bk[j] = (int)(d >> BKT_SHIFT);
        val[j] = s | ((d & (BKT_NODES - 1)) << 16);
        pos[j] = atomicAdd(&cnt[bk[j]], 1);
      } else bk[j] = -1;
    }
  }
  __syncthreads();
  for (int t = tid; t < NB; t += 256)
    gbase[t] = cnt[t] ? atomicAdd(&gcursor[t], cnt[t]) : 0;
  __syncthreads();
#pragma unroll
  for (int j = 0; j < 16; ++j)
    if (bk[j] >= 0) pairs[(size_t)bk[j] * CAP + gbase[bk[j]] + pos[j]] = val[j];
}

// ---- per-bucket counting sort -> 8-padded col segments (static base b*CAP) + row_start/deg/dis
__global__ __launch_bounds__(256) void build_kernel(const uint32_t* __restrict__ pairs,
                                                    const int* __restrict__ gcursor,
                                                    int* __restrict__ row_start,
                                                    int* __restrict__ degv,
                                                    float* __restrict__ dis,
                                                    unsigned short* __restrict__ col, int N) {
  __shared__ int hcnt[BKT_NODES], hcur[BKT_NODES], hend[BKT_NODES];
  __shared__ int s[BKT_NODES];
  const int b = blockIdx.x;
  const int tid = threadIdx.x;
  const int e0 = b * CAP;
  const int e1 = e0 + gcursor[b];
  if (tid < BKT_NODES) hcnt[tid] = 0;
  __syncthreads();
  for (int i = e0 + tid; i < e1; i += 256) atomicAdd(&hcnt[pairs[i] >> 16], 1);
  __syncthreads();
  int v = 0, v8 = 0;
  if (tid < BKT_NODES) { v = hcnt[tid]; v8 = (v + 7) & ~7; s[tid] = v8; }
  __syncthreads();
  for (int off = 1; off < BKT_NODES; off <<= 1) {
    int t = 0;
    if (tid < BKT_NODES && tid >= off) t = s[tid - off];
    __syncthreads();
    if (tid < BKT_NODES) s[tid] += t;
    __syncthreads();
  }
  if (tid < BKT_NODES) {
    const int st = e0 + s[tid] - v8;        // padded total per bucket <= CAP by construction
    hcur[tid] = st;
    hend[tid] = st + v8;
    const int node = b * BKT_NODES + tid;
    if (node < N) {
      row_start[node] = st;
      degv[node] = v;
      dis[node] = rsqrtf((float)(v + 1));   // deg incl self-loop
    }
  }
  __syncthreads();
  for (int i = e0 + tid; i < e1; i += 256) {
    uint32_t pv = pairs[i];
    int p = atomicAdd(&hcur[pv >> 16], 1);
    col[p] = (unsigned short)(pv & 0xFFFFu);
  }
  __syncthreads();
  if (tid < BKT_NODES) {
    for (int p = hcur[tid]; p < hend[tid]; ++p) col[p] = (unsigned short)N;  // sentinel
  }
}

// ---- prep: cvec reduce (blocks 0..255) + sentinel zeroing (block 256)
__global__ __launch_bounds__(256) void prep_kernel(const float* __restrict__ W2,
                                                   const float* __restrict__ b1,
                                                   float* __restrict__ cv,
                                                   unsigned short* __restrict__ g,
                                                   unsigned short* __restrict__ t,
                                                   float* __restrict__ dis, int N, int NR) {
  const int b = blockIdx.x, tid = threadIdx.x;
  if (b < 256) {                       // cv[j] = sum_k b1[k]*W2[k][j]
    __shared__ float s[256];
    const int j = b;
    s[tid] = b1[tid] * W2[tid * F + j];
    __syncthreads();
    for (int off = 128; off > 0; off >>= 1) {
      if (tid < off) s[tid] += s[tid + off];
      __syncthreads();
    }
    if (tid == 0) cv[j] = s[0];
  } else {                             // sentinel rows (row N of each chunk) + dis[N]
    const int c = tid >> 5, f = tid & 31;
    g[((size_t)c * NR + N) * CW + f] = 0;
    t[((size_t)c * NR + N) * CW + f] = 0;
    if (tid == 0) dis[N] = 0.f;
  }
}

// ---- self-contained W12 GEMM: W12T[n][k] = sum_m W2[m][n] * W1[k][m]  (2 blocks of 128 rows)
// A[n][m] = W2[m*256+n] (fp32 strided, converted inline); BT[k][m] = W1[k*256+m] (fp32 rows).
__global__ __launch_bounds__(256, 1) void wgemm_kernel(const float* __restrict__ W1,
                                                       const float* __restrict__ W2,
                                                       unsigned short* __restrict__ W12T) {
  const int tid = threadIdx.x;
  const int w = tid >> 6;
  const int l = tid & 63;
  const int row0 = blockIdx.x * 128 + (w >> 1) * 64;
  const int col0 = (w & 1) * 128;
  const int lr = l & 15;
  const int lk = (l >> 4) * 8;

  f32x4 acc[4][8] = {};
  for (int kk = 0; kk < F; kk += 32) {
    bf16x8 a[4], b[8];
#pragma unroll
    for (int i = 0; i < 4; ++i) {
      const int r = row0 + i * 16 + lr;
      bf16x8 af;
#pragma unroll
      for (int m = 0; m < 8; ++m)
        af[m] = (short)f2bf(W2[(size_t)(kk + lk + m) * F + r]);   // W2 column r (strided)
      a[i] = af;
    }
#pragma unroll
    for (int j = 0; j < 8; ++j) {
      const int c = col0 + j * 16 + lr;
      const float4v* pB = reinterpret_cast<const float4v*>(W1 + (size_t)c * F + kk + lk);
      float4v u0 = pB[0], u1 = pB[1];
      bf16x8 bf;
      bf[0] = (short)f2bf(u0[0]); bf[1] = (short)f2bf(u0[1]);
      bf[2] = (short)f2bf(u0[2]); bf[3] = (short)f2bf(u0[3]);
      bf[4] = (short)f2bf(u1[0]); bf[5] = (short)f2bf(u1[1]);
      bf[6] = (short)f2bf(u1[2]); bf[7] = (short)f2bf(u1[3]);
      b[j] = bf;
    }
#pragma unroll
    for (int i = 0; i < 4; ++i)
#pragma unroll
      for (int j = 0; j < 8; ++j)
        acc[i][j] = __builtin_amdgcn_mfma_f32_16x16x32_bf16(a[i], b[j], acc[i][j], 0, 0, 0);
  }
  const int orow = (l >> 4) * 4;
  const int ocol = l & 15;
#pragma unroll
  for (int i = 0; i < 4; ++i)
#pragma unroll
    for (int r = 0; r < 4; ++r) {
      const int row = row0 + i * 16 + orow + r;
#pragma unroll
      for (int j = 0; j < 8; ++j)
        W12T[(size_t)row * F + col0 + j * 16 + ocol] = f2bf(acc[i][j][r]);
    }
}

// ---- main GEMM: block tile 128x256 (A read exactly once). A fp32 row-major [M][256].
// G chunk-major [8][NR][32], scaled by dis.
__global__ __launch_bounds__(256, 1) void gemm_kernel(
    const float* __restrict__ A,
    const unsigned short* __restrict__ BT,  // [256][256] bf16 (W12 transposed)
    const float* __restrict__ dis,
    unsigned short* __restrict__ G, int M, int NR)
{
  const int tid = threadIdx.x;
  const int w = tid >> 6;
  const int l = tid & 63;
  const int row0 = blockIdx.x * 128 + (w >> 1) * 64;
  const int col0 = (w & 1) * 128;
  const int lr = l & 15;
  const int lk = (l >> 4) * 8;

  f32x4 acc[4][8] = {};
  for (int kk = 0; kk < F; kk += 32) {
    bf16x8 a[4], b[8];
#pragma unroll
    for (int i = 0; i < 4; ++i) {
      int r = row0 + i * 16 + lr;
      r = r < M ? r : M - 1;  // clamp tail rows (stores guarded)
      const float4v* pA = reinterpret_cast<const float4v*>(A + (size_t)r * F + kk + lk);
      float4v u0 = pA[0], u1 = pA[1];
      bf16x8 af;
      af[0] = (short)f2bf(u0[0]); af[1] = (short)f2bf(u0[1]);
      af[2] = (short)f2bf(u0[2]); af[3] = (short)f2bf(u0[3]);
      af[4] = (short)f2bf(u1[0]); af[5] = (short)f2bf(u1[1]);
      af[6] = (short)f2bf(u1[2]); af[7] = (short)f2bf(u1[3]);
      a[i] = af;
    }
#pragma unroll
    for (int j = 0; j < 8; ++j)
      b[j] = *reinterpret_cast<const bf16x8*>(BT + (size_t)(col0 + j * 16 + lr) * F + kk + lk);
#pragma unroll
    for (int i = 0; i < 4; ++i)
#pragma unroll
      for (int j = 0; j < 8; ++j)
        acc[i][j] = __builtin_amdgcn_mfma_f32_16x16x32_bf16(a[i], b[j], acc[i][j], 0, 0, 0);
  }
  // C/D layout: col = lane&15, row = (lane>>4)*4 + reg
  const int orow = (l >> 4) * 4;
  const int ocol = l & 15;
#pragma unroll
  for (int i = 0; i < 4; ++i) {
#pragma unroll
    for (int r = 0; r < 4; ++r) {
      int row = row0 + i * 16 + orow + r;
      if (row < M) {
        float d = dis[row];
#pragma unroll
        for (int j = 0; j < 8; ++j) {
          int c = (col0 >> 5) + (j >> 1);          // output chunk 0..7
          int f = ((j & 1) << 4) + ocol;           // feature within chunk
          G[((size_t)c * NR + row) * CW + f] = f2bf(acc[i][j][r] * d);
        }
      }
    }
  }
}

// ---- chunked aggregation over Gc[c][NR][32], chunk pinned to XCD (blockIdx&7).
// Wave = 16 node-groups x 4 lanes (16B/lane). At the per-CU MSHR x L2-latency ceiling.
// LAST=0: t' = S·Â·G = d^2*(sum+self), bf16 chunk-major; blocks >= 2048 compute rsum (Â·1).
// LAST=1: out = S(A+I)·t' + r·c + b2, PReLU, fp32 row-major.
template <int LAST>
__global__ __launch_bounds__(256) void aggregate_kernel(
    const unsigned short* __restrict__ Gc, const float* __restrict__ dis,
    const int* __restrict__ row_start, const int* __restrict__ degv,
    const unsigned short* __restrict__ col,
    const float* __restrict__ bias, const float* __restrict__ pa,
    float* __restrict__ rv, const float* __restrict__ cvec,
    void* __restrict__ outv, int N, int NR)
{
  if constexpr (!LAST) {
    if (blockIdx.x >= 2048) {          // fused rsum: rv[n] = dis[n]*(sum dis[col] + dis[n])
      const int n = (blockIdx.x - 2048) * 256 + threadIdx.x;
      if (n < N) {
        const int s0 = row_start[n];
        const int ntr = (degv[n] + 7) >> 3;
        float sum = dis[n];  // self loop
        for (int tI = 0; tI < ntr; ++tI) {
          const u32x4 cvv = *reinterpret_cast<const u32x4*>(col + s0 + tI * 8);
          sum += dis[cvv.x & 0xFFFFu] + dis[cvv.x >> 16] + dis[cvv.y & 0xFFFFu] + dis[cvv.y >> 16]
               + dis[cvv.z & 0xFFFFu] + dis[cvv.z >> 16] + dis[cvv.w & 0xFFFFu] + dis[cvv.w >> 16];
        }
        rv[n] = dis[n] * sum;
      }
      return;
    }
  }
  const int c   = blockIdx.x & 7;            // chunk == XCD
  const int cb  = blockIdx.x >> 3;           // block within chunk [0,256)
  const int wv  = threadIdx.x >> 6;
  const int l   = threadIdx.x & 63;
  const int grp = l >> 2;                    // node sub-index 0..15
  const int f8  = (l & 3) * 8;               // 8 features within chunk (16B per lane)
  const unsigned short* __restrict__ base = Gc + (size_t)c * NR * CW + f8;
  const int fb = c * CW + f8;
  float bv[8], qv[8], cvv[8];
  if constexpr (LAST) {
    const float4v* bp = reinterpret_cast<const float4v*>(bias + fb);
    const float4v* qp = reinterpret_cast<const float4v*>(pa + fb);
    const float4v* cp = reinterpret_cast<const float4v*>(cvec + fb);
    float4v b0 = bp[0], b1 = bp[1], q0 = qp[0], q1 = qp[1], c0 = cp[0], c1 = cp[1];
#pragma unroll
    for (int i = 0; i < 4; ++i) {
      bv[i] = b0[i]; bv[4 + i] = b1[i];
      qv[i] = q0[i]; qv[4 + i] = q1[i];
      cvv[i] = c0[i]; cvv[4 + i] = c1[i];
    }
  }

  for (int n0 = cb * 64 + wv * 16; n0 < N; n0 += 256 * 64) {
    const int n = n0 + grp;
    if (n >= N) continue;
    float a0, a1, a2, a3, a4, a5, a6, a7;
    {
      const u32x4 v = *reinterpret_cast<const u32x4*>(base + (size_t)n * CW);  // self loop
      a0 = asf(v.x << 16); a1 = asf(v.x & 0xFFFF0000u);
      a2 = asf(v.y << 16); a3 = asf(v.y & 0xFFFF0000u);
      a4 = asf(v.z << 16); a5 = asf(v.z & 0xFFFF0000u);
      a6 = asf(v.w << 16); a7 = asf(v.w & 0xFFFF0000u);
    }
    const int s = row_start[n];
    const int ntr = (degv[n] + 7) >> 3;
    for (int tI = 0; tI < ntr; ++tI) {
      const u32x4 cv = *reinterpret_cast<const u32x4*>(col + s + tI * 8);  // 8 cols (bcast x4)
      const u32x4 g0 = *reinterpret_cast<const u32x4*>(base + (size_t)(cv.x & 0xFFFFu) * CW);
      const u32x4 g1 = *reinterpret_cast<const u32x4*>(base + (size_t)(cv.x >> 16) * CW);
      const u32x4 g2 = *reinterpret_cast<const u32x4*>(base + (size_t)(cv.y & 0xFFFFu) * CW);
      const u32x4 g3 = *reinterpret_cast<const u32x4*>(base + (size_t)(cv.y >> 16) * CW);
      const u32x4 g4 = *reinterpret_cast<const u32x4*>(base + (size_t)(cv.z & 0xFFFFu) * CW);
      const u32x4 g5 = *reinterpret_cast<const u32x4*>(base + (size_t)(cv.z >> 16) * CW);
      const u32x4 g6 = *reinterpret_cast<const u32x4*>(base + (size_t)(cv.w & 0xFFFFu) * CW);
      const u32x4 g7 = *reinterpret_cast<const u32x4*>(base + (size_t)(cv.w >> 16) * CW);
#define ACC8(g) \
      a0 += asf(g.x << 16); a1 += asf(g.x & 0xFFFF0000u); \
      a2 += asf(g.y << 16); a3 += asf(g.y & 0xFFFF0000u); \
      a4 += asf(g.z << 16); a5 += asf(g.z & 0xFFFF0000u); \
      a6 += asf(g.w << 16); a7 += asf(g.w & 0xFFFF0000u);
      ACC8(g0) ACC8(g1) ACC8(g2) ACC8(g3) ACC8(g4) ACC8(g5) ACC8(g6) ACC8(g7)
#undef ACC8
    }
    const float d = dis[n];
    if constexpr (LAST) {
      const float rn = rv[n];
      float r[8] = {a0, a1, a2, a3, a4, a5, a6, a7};
      float4v o0, o1;
#pragma unroll
      for (int i = 0; i < 8; ++i) {
        float ri = fmaf(r[i], d, fmaf(rn, cvv[i], bv[i]));
        ri = fmaxf(ri, 0.f) + qv[i] * fminf(ri, 0.f);
        if (i < 4) o0[i] = ri; else o1[i - 4] = ri;
      }
      float* op = (float*)outv + (size_t)n * F + fb;
      __builtin_nontemporal_store(o0, reinterpret_cast<float4v*>(op));
      __builtin_nontemporal_store(o1, reinterpret_cast<float4v*>(op + 4));
    } else {
      const float dd = d * d;   // d^2: S(A+I) of this hop + inner S of the NEXT hop
      u32x4 o;
      o.x = (uint32_t)f2bf(a0 * dd) | ((uint32_t)f2bf(a1 * dd) << 16);
      o.y = (uint32_t)f2bf(a2 * dd) | ((uint32_t)f2bf(a3 * dd) << 16);
      o.z = (uint32_t)f2bf(a4 * dd) | ((uint32_t)f2bf(a5 * dd) << 16);
      o.w = (uint32_t)f2bf(a6 * dd) | ((uint32_t)f2bf(a7 * dd) << 16);
      __builtin_nontemporal_store(o, reinterpret_cast<u32x4*>(
          (unsigned short*)outv + ((size_t)c * NR + n) * CW + f8));
    }
  }
}

extern "C" void kernel_launch(void* const* d_in, const int* in_sizes, int n_in,
                              void* d_out, int out_size, void* d_ws, size_t ws_size,
                              hipStream_t stream) {
  const float* x  = (const float*)d_in[0];
  const int* ei   = (const int*)d_in[1];
  const float* W1 = (const float*)d_in[2];
  const float* b1 = (const float*)d_in[3];
  const float* W2 = (const float*)d_in[4];
  const float* b2 = (const float*)d_in[5];
  const float* pa = (const float*)d_in[6];

  const int N = in_sizes[0] / F;
  const int E = in_sizes[1] / 2;
  const int NR = N + 1;                              // +1 sentinel (zero) row per chunk
  const int NB = (N + BKT_NODES - 1) >> BKT_SHIFT;   // 391 for N=50000
  const int* src  = ei;
  const int* dstv = ei + E;

  // ws bump allocator
  char* p = (char*)d_ws;
  auto alloc = [&](size_t bytes) -> char* {
    char* r = p; p += (bytes + 255) & ~(size_t)255; return r;
  };
  int*   gcursor     = (int*)alloc(sizeof(int) * MAXNB);
  int*   row_start   = (int*)alloc(sizeof(int) * (size_t)N);
  int*   degv        = (int*)alloc(sizeof(int) * (size_t)N);
  float* dis         = (float*)alloc(sizeof(float) * (size_t)(N + 1));  // +1: dis[N]=0 sentinel
  float* rv          = (float*)alloc(sizeof(float) * (size_t)N);
  float* cv          = (float*)alloc(sizeof(float) * F);
  unsigned short* col  = (unsigned short*)alloc(sizeof(short) * (size_t)NB * CAP);
  unsigned short* W12T = (unsigned short*)alloc(sizeof(short) * F * F);
  unsigned short* g   = (unsigned short*)alloc(sizeof(short) * (size_t)NR * F);
  unsigned short* t   = (unsigned short*)alloc(sizeof(short) * (size_t)NR * F);
  uint32_t* pairs = (uint32_t*)t;  // alias: pairs dead (after build) before t is written (agg0)

  hipMemsetAsync(gcursor, 0, sizeof(int) * MAXNB, stream);
  // W12T = (W1·W2)^T — self-contained, no deps
  wgemm_kernel<<<2, 256, 0, stream>>>(W1, W2, W12T);
  scatter_kernel<<<(E + CHUNK - 1) / CHUNK, 256, 0, stream>>>(src, dstv, gcursor, pairs, E, NB);
  build_kernel<<<NB, 256, 0, stream>>>(pairs, gcursor, row_start, degv, dis, col, N);
  prep_kernel<<<257, 256, 0, stream>>>(W2, b1, cv, g, t, dis, N, NR);

  // H = dis .* (bf16(x) @ W12), chunk-major   (g = S·H); A read exactly once (BN=256)
  gemm_kernel<<<(N + 127) / 128, 256, 0, stream>>>(x, W12T, dis, g, N, NR);
  // t' = S·Â·H  (+ fused rsum in blocks >= 2048)
  aggregate_kernel<0><<<2048 + (N + 255) / 256, 256, 0, stream>>>(
      g, dis, row_start, degv, col, nullptr, nullptr, rv, nullptr, t, N, NR);
  // out = S(A+I)·t' + r·(b1ᵀW2) + b2, PReLU -> fp32  ( = ÂÂH + r·c + b2 )
  aggregate_kernel<1><<<2048, 256, 0, stream>>>(t, dis, row_start, degv, col,
                                                b2, pa, rv, cv, d_out, N, NR);
}

// Round 14
// 255.514 us; speedup vs baseline: 1.0398x; 1.0398x over previous
//
#include <hip/hip_runtime.h>
#include <stdint.h>

typedef __attribute__((ext_vector_type(8))) short bf16x8;   // 8 bf16 = 4 VGPRs (MFMA operand)
typedef __attribute__((ext_vector_type(4))) float f32x4;    // MFMA acc
typedef __attribute__((ext_vector_type(4))) float float4v;
typedef __attribute__((ext_vector_type(4))) unsigned int u32x4;  // native 16B vector

#define F 256
#define NCHUNK 8                  // feature chunks == XCD count
#define CW 32                     // chunk width; N*CW*2B = 3.2MB <= 4MB per-XCD L2
#define BKT_SHIFT 7               // 128 nodes per bucket
#define BKT_NODES 128
#define MAXNB 512                 // N <= 65536
#define CAP 6144                  // fixed bucket capacity (mean 4092+pad<=896; +32sigma safe)
#define CHUNK 4096                // edges per block in scatter (long runs -> fewer dirty lines)

static __device__ __forceinline__ float asf(uint32_t u) {
  union { uint32_t u; float f; } x; x.u = u; return x.f;
}
static __device__ __forceinline__ unsigned short f2bf(float f) {
  union { float f; uint32_t u; } x; x.f = f;
  uint32_t u = x.u;
  return (unsigned short)((u + 0x7FFFu + ((u >> 16) & 1u)) >> 16);  // RNE, matches np/jax cast
}

// ---- scatter edges into fixed-capacity bucket regions: pairs[b*CAP + pos] = src | dstlocal<<16
// gcursor[b] accumulates the bucket count (no separate histogram/scan pass).
__global__ __launch_bounds__(256) void scatter_kernel(const int* __restrict__ src,
                                                      const int* __restrict__ dst,
                                                      int* __restrict__ gcursor,
                                                      uint32_t* __restrict__ pairs, int E, int NB) {
  __shared__ int cnt[MAXNB];
  __shared__ int gbase[MAXNB];
  const int tid = threadIdx.x;
  for (int t = tid; t < MAXNB; t += 256) cnt[t] = 0;
  __syncthreads();
  const int base = blockIdx.x * CHUNK;
  uint32_t val[16];
  int bk[16], pos[16];
  if (base + CHUNK <= E) {                 // fast path: full chunk, vector loads
    const int i0 = base + tid * 16;
#pragma unroll
    for (int q = 0; q < 4; ++q) {
      const u32x4 s0 = *reinterpret_cast<const u32x4*>(src + i0 + q * 4);
      const u32x4 d0 = *reinterpret_cast<const u32x4*>(dst + i0 + q * 4);
      uint32_t sv[4] = {s0.x, s0.y, s0.z, s0.w};
      uint32_t dv[4] = {d0.x, d0.y, d0.z, d0.w};
#pragma unroll
      for (int j = 0; j < 4; ++j) {
        int jj = q * 4 + j;
        bk[jj] = (int)(dv[j] >> BKT_SHIFT);
        val[jj] = sv[j] | ((dv[j] & (BKT_NODES - 1)) << 16);
        pos[jj] = atomicAdd(&cnt[bk[jj]], 1);
      }
    }
  } else {                                  // tail block: guarded scalar
#pragma unroll
    for (int j = 0; j < 16; ++j) {
      int i = base + tid * 16 + j;
      if (i < E) {
        uint32_t s = (uint32_t)src[i], d = (uint32_t)dst[i];
        bk[j] = (int)(d >> BKT_SHIFT);
        val[j] = s | ((d & (BKT_NODES - 1)) << 16);
        pos[j] = atomicAdd(&cnt[bk[j]], 1);
      } else bk[j] = -1;
    }
  }
  __syncthreads();
  for (int t = tid; t < NB; t += 256)
    gbase[t] = cnt[t] ? atomicAdd(&gcursor[t], cnt[t]) : 0;
  __syncthreads();
#pragma unroll
  for (int j = 0; j < 16; ++j)
    if (bk[j] >= 0) pairs[(size_t)bk[j] * CAP + gbase[bk[j]] + pos[j]] = val[j];
}

// ---- per-bucket counting sort -> 8-padded col segments (static base b*CAP) + row_start/deg/dis
__global__ __launch_bounds__(256) void build_kernel(const uint32_t* __restrict__ pairs,
                                                    const int* __restrict__ gcursor,
                                                    int* __restrict__ row_start,
                                                    int* __restrict__ degv,
                                                    float* __restrict__ dis,
                                                    unsigned short* __restrict__ col, int N) {
  __shared__ int hcnt[BKT_NODES], hcur[BKT_NODES], hend[BKT_NODES];
  __shared__ int s[BKT_NODES];
  const int b = blockIdx.x;
  const int tid = threadIdx.x;
  const int e0 = b * CAP;
  const int e1 = e0 + gcursor[b];
  if (tid < BKT_NODES) hcnt[tid] = 0;
  __syncthreads();
  for (int i = e0 + tid; i < e1; i += 256) atomicAdd(&hcnt[pairs[i] >> 16], 1);
  __syncthreads();
  int v = 0, v8 = 0;
  if (tid < BKT_NODES) { v = hcnt[tid]; v8 = (v + 7) & ~7; s[tid] = v8; }
  __syncthreads();
  for (int off = 1; off < BKT_NODES; off <<= 1) {
    int t = 0;
    if (tid < BKT_NODES && tid >= off) t = s[tid - off];
    __syncthreads();
    if (tid < BKT_NODES) s[tid] += t;
    __syncthreads();
  }
  if (tid < BKT_NODES) {
    const int st = e0 + s[tid] - v8;        // padded total per bucket <= CAP by construction
    hcur[tid] = st;
    hend[tid] = st + v8;
    const int node = b * BKT_NODES + tid;
    if (node < N) {
      row_start[node] = st;
      degv[node] = v;
      dis[node] = rsqrtf((float)(v + 1));   // deg incl self-loop
    }
  }
  __syncthreads();
  for (int i = e0 + tid; i < e1; i += 256) {
    uint32_t pv = pairs[i];
    int p = atomicAdd(&hcur[pv >> 16], 1);
    col[p] = (unsigned short)(pv & 0xFFFFu);
  }
  __syncthreads();
  if (tid < BKT_NODES) {
    for (int p = hcur[tid]; p < hend[tid]; ++p) col[p] = (unsigned short)N;  // sentinel
  }
}

// ---- fused prep: W1 convert, W2 transpose, cvec reduce, sentinel zeroing, rsum (Â·1)
// grid = 769 + ceil(N/256) blocks. Runs after build (needs row_start/degv/dis; pairs dead).
__global__ __launch_bounds__(256) void prep_kernel(const float* __restrict__ W1,
                                                   const float* __restrict__ W2,
                                                   const float* __restrict__ b1,
                                                   unsigned short* __restrict__ W1B,
                                                   unsigned short* __restrict__ W2T,
                                                   float* __restrict__ cv,
                                                   unsigned short* __restrict__ g,
                                                   unsigned short* __restrict__ t,
                                                   float* __restrict__ dis,
                                                   const int* __restrict__ row_start,
                                                   const int* __restrict__ degv,
                                                   const unsigned short* __restrict__ col,
                                                   float* __restrict__ rv,
                                                   int N, int NR) {
  const int b = blockIdx.x, tid = threadIdx.x;
  if (b < 256) {                       // W1B = bf16(W1)
    int i = b * 256 + tid;
    W1B[i] = f2bf(W1[i]);
  } else if (b < 512) {                // W2T[n][k] = bf16(W2[k][n])
    int i = (b - 256) * 256 + tid;
    W2T[i] = f2bf(W2[(i & 255) * 256 + (i >> 8)]);
  } else if (b < 768) {                // cv[j] = sum_k b1[k]*W2[k][j]
    __shared__ float s[256];
    const int j = b - 512;
    s[tid] = b1[tid] * W2[tid * F + j];
    __syncthreads();
    for (int off = 128; off > 0; off >>= 1) {
      if (tid < off) s[tid] += s[tid + off];
      __syncthreads();
    }
    if (tid == 0) cv[j] = s[0];
  } else if (b == 768) {               // sentinel rows (row N of each chunk) + dis[N]
    const int c = tid >> 5, f = tid & 31;
    g[((size_t)c * NR + N) * CW + f] = 0;
    t[((size_t)c * NR + N) * CW + f] = 0;
    if (tid == 0) dis[N] = 0.f;
  } else {                             // rsum: rv[n] = dis[n]*(sum dis[col] + dis[n])
    const int n = (b - 769) * 256 + tid;
    if (n < N) {
      const int s0 = row_start[n];
      const int ntr = (degv[n] + 7) >> 3;
      float sum = dis[n];  // self loop
      for (int tI = 0; tI < ntr; ++tI) {
        const u32x4 cvv = *reinterpret_cast<const u32x4*>(col + s0 + tI * 8);
        sum += dis[cvv.x & 0xFFFFu] + dis[cvv.x >> 16] + dis[cvv.y & 0xFFFFu] + dis[cvv.y >> 16]
             + dis[cvv.z & 0xFFFFu] + dis[cvv.z >> 16] + dis[cvv.w & 0xFFFFu] + dis[cvv.w >> 16];
      }
      rv[n] = dis[n] * sum;
    }
  }
}

// ---- GEMM: block tile 128x256 (full output width -> A read exactly once).
// 4 waves: (w>>1) = 64-row half, (w&1) = 128-col half; each wave 4x8 frags of 16x16x32.
// A_FP32=1: A fp32 row-major [M][256].  A_FP32=0: A bf16 row-major [M][256].
// PLAIN=1: G row-major bf16, no dis scale.  PLAIN=0: G chunk-major [8][NR][32], scaled by dis.
template <int A_FP32, int PLAIN>
__global__ __launch_bounds__(256, 1) void gemm_kernel(
    const void* __restrict__ Av,
    const unsigned short* __restrict__ BT,  // [256][256] bf16
    const float* __restrict__ dis,
    unsigned short* __restrict__ G, int M, int NR)
{
  const int tid = threadIdx.x;
  const int w = tid >> 6;
  const int l = tid & 63;
  const int row0 = blockIdx.x * 128 + (w >> 1) * 64;
  const int col0 = (w & 1) * 128;
  const int lr = l & 15;
  const int lk = (l >> 4) * 8;

  f32x4 acc[4][8] = {};
  for (int kk = 0; kk < F; kk += 32) {
    bf16x8 a[4], b[8];
#pragma unroll
    for (int i = 0; i < 4; ++i) {
      int r = row0 + i * 16 + lr;
      r = r < M ? r : M - 1;  // clamp tail rows (stores guarded)
      if constexpr (A_FP32) {
        const float* A = (const float*)Av;
        const float4v* pA = reinterpret_cast<const float4v*>(A + (size_t)r * F + kk + lk);
        float4v u0 = pA[0], u1 = pA[1];
        bf16x8 af;
        af[0] = (short)f2bf(u0[0]); af[1] = (short)f2bf(u0[1]);
        af[2] = (short)f2bf(u0[2]); af[3] = (short)f2bf(u0[3]);
        af[4] = (short)f2bf(u1[0]); af[5] = (short)f2bf(u1[1]);
        af[6] = (short)f2bf(u1[2]); af[7] = (short)f2bf(u1[3]);
        a[i] = af;
      } else {
        const unsigned short* A = (const unsigned short*)Av;
        a[i] = *reinterpret_cast<const bf16x8*>(A + (size_t)r * F + kk + lk);
      }
    }
#pragma unroll
    for (int j = 0; j < 8; ++j)
      b[j] = *reinterpret_cast<const bf16x8*>(BT + (size_t)(col0 + j * 16 + lr) * F + kk + lk);
#pragma unroll
    for (int i = 0; i < 4; ++i)
#pragma unroll
      for (int j = 0; j < 8; ++j)
        acc[i][j] = __builtin_amdgcn_mfma_f32_16x16x32_bf16(a[i], b[j], acc[i][j], 0, 0, 0);
  }
  // C/D layout: col = lane&15, row = (lane>>4)*4 + reg
  const int orow = (l >> 4) * 4;
  const int ocol = l & 15;
#pragma unroll
  for (int i = 0; i < 4; ++i) {
#pragma unroll
    for (int r = 0; r < 4; ++r) {
      int row = row0 + i * 16 + orow + r;
      if (row < M) {
        if constexpr (PLAIN) {
#pragma unroll
          for (int j = 0; j < 8; ++j)
            G[(size_t)row * F + col0 + j * 16 + ocol] = f2bf(acc[i][j][r]);
        } else {
          float d = dis[row];
#pragma unroll
          for (int j = 0; j < 8; ++j) {
            int c = (col0 >> 5) + (j >> 1);          // output chunk 0..7
            int f = ((j & 1) << 4) + ocol;           // feature within chunk
            G[((size_t)c * NR + row) * CW + f] = f2bf(acc[i][j][r] * d);
          }
        }
      }
    }
  }
}

// ---- chunked aggregation over Gc[c][NR][32], chunk pinned to XCD.
// grid = 2048; chunk = blockIdx&7. Wave = 16 node-groups x 4 lanes (16B = 8 features per
// lane). 8-padded segments (sentinel id N -> zero row): one u32x4 col load + 8 u32x4
// gathers in flight per group. At the per-CU MSHR x L2-latency ceiling (~0.3 lines/cy).
// LAST=0: t' = S·Â·G = d^2*(sum+self), bf16 chunk-major.
// LAST=1: out = S(A+I)·t' + r·c + b2, PReLU, fp32 row-major.
template <int LAST>
__global__ __launch_bounds__(256) void aggregate_kernel(
    const unsigned short* __restrict__ Gc, const float* __restrict__ dis,
    const int* __restrict__ row_start, const int* __restrict__ degv,
    const unsigned short* __restrict__ col,
    const float* __restrict__ bias, const float* __restrict__ pa,
    const float* __restrict__ rv, const float* __restrict__ cvec,
    void* __restrict__ outv, int N, int NR)
{
  const int c   = blockIdx.x & 7;            // chunk == XCD
  const int cb  = blockIdx.x >> 3;           // block within chunk [0,256)
  const int wv  = threadIdx.x >> 6;
  const int l   = threadIdx.x & 63;
  const int grp = l >> 2;                    // node sub-index 0..15
  const int f8  = (l & 3) * 8;               // 8 features within chunk (16B per lane)
  const unsigned short* __restrict__ base = Gc + (size_t)c * NR * CW + f8;
  const int fb = c * CW + f8;
  float bv[8], qv[8], cvv[8];
  if constexpr (LAST) {
    const float4v* bp = reinterpret_cast<const float4v*>(bias + fb);
    const float4v* qp = reinterpret_cast<const float4v*>(pa + fb);
    const float4v* cp = reinterpret_cast<const float4v*>(cvec + fb);
    float4v b0 = bp[0], b1 = bp[1], q0 = qp[0], q1 = qp[1], c0 = cp[0], c1 = cp[1];
#pragma unroll
    for (int i = 0; i < 4; ++i) {
      bv[i] = b0[i]; bv[4 + i] = b1[i];
      qv[i] = q0[i]; qv[4 + i] = q1[i];
      cvv[i] = c0[i]; cvv[4 + i] = c1[i];
    }
  }

  for (int n0 = cb * 64 + wv * 16; n0 < N; n0 += 256 * 64) {
    const int n = n0 + grp;
    if (n >= N) continue;
    float a0, a1, a2, a3, a4, a5, a6, a7;
    {
      const u32x4 v = *reinterpret_cast<const u32x4*>(base + (size_t)n * CW);  // self loop
      a0 = asf(v.x << 16); a1 = asf(v.x & 0xFFFF0000u);
      a2 = asf(v.y << 16); a3 = asf(v.y & 0xFFFF0000u);
      a4 = asf(v.z << 16); a5 = asf(v.z & 0xFFFF0000u);
      a6 = asf(v.w << 16); a7 = asf(v.w & 0xFFFF0000u);
    }
    const int s = row_start[n];
    const int ntr = (degv[n] + 7) >> 3;
    for (int tI = 0; tI < ntr; ++tI) {
      const u32x4 cv = *reinterpret_cast<const u32x4*>(col + s + tI * 8);  // 8 cols (bcast x4)
      const u32x4 g0 = *reinterpret_cast<const u32x4*>(base + (size_t)(cv.x & 0xFFFFu) * CW);
      const u32x4 g1 = *reinterpret_cast<const u32x4*>(base + (size_t)(cv.x >> 16) * CW);
      const u32x4 g2 = *reinterpret_cast<const u32x4*>(base + (size_t)(cv.y & 0xFFFFu) * CW);
      const u32x4 g3 = *reinterpret_cast<const u32x4*>(base + (size_t)(cv.y >> 16) * CW);
      const u32x4 g4 = *reinterpret_cast<const u32x4*>(base + (size_t)(cv.z & 0xFFFFu) * CW);
      const u32x4 g5 = *reinterpret_cast<const u32x4*>(base + (size_t)(cv.z >> 16) * CW);
      const u32x4 g6 = *reinterpret_cast<const u32x4*>(base + (size_t)(cv.w & 0xFFFFu) * CW);
      const u32x4 g7 = *reinterpret_cast<const u32x4*>(base + (size_t)(cv.w >> 16) * CW);
#define ACC8(g) \
      a0 += asf(g.x << 16); a1 += asf(g.x & 0xFFFF0000u); \
      a2 += asf(g.y << 16); a3 += asf(g.y & 0xFFFF0000u); \
      a4 += asf(g.z << 16); a5 += asf(g.z & 0xFFFF0000u); \
      a6 += asf(g.w << 16); a7 += asf(g.w & 0xFFFF0000u);
      ACC8(g0) ACC8(g1) ACC8(g2) ACC8(g3) ACC8(g4) ACC8(g5) ACC8(g6) ACC8(g7)
#undef ACC8
    }
    const float d = dis[n];
    if constexpr (LAST) {
      const float rn = rv[n];
      float r[8] = {a0, a1, a2, a3, a4, a5, a6, a7};
      float4v o0, o1;
#pragma unroll
      for (int i = 0; i < 8; ++i) {
        float ri = fmaf(r[i], d, fmaf(rn, cvv[i], bv[i]));
        ri = fmaxf(ri, 0.f) + qv[i] * fminf(ri, 0.f);
        if (i < 4) o0[i] = ri; else o1[i - 4] = ri;
      }
      float* op = (float*)outv + (size_t)n * F + fb;
      __builtin_nontemporal_store(o0, reinterpret_cast<float4v*>(op));
      __builtin_nontemporal_store(o1, reinterpret_cast<float4v*>(op + 4));
    } else {
      const float dd = d * d;   // d^2: S(A+I) of this hop + inner S of the NEXT hop
      u32x4 o;
      o.x = (uint32_t)f2bf(a0 * dd) | ((uint32_t)f2bf(a1 * dd) << 16);
      o.y = (uint32_t)f2bf(a2 * dd) | ((uint32_t)f2bf(a3 * dd) << 16);
      o.z = (uint32_t)f2bf(a4 * dd) | ((uint32_t)f2bf(a5 * dd) << 16);
      o.w = (uint32_t)f2bf(a6 * dd) | ((uint32_t)f2bf(a7 * dd) << 16);
      __builtin_nontemporal_store(o, reinterpret_cast<u32x4*>(
          (unsigned short*)outv + ((size_t)c * NR + n) * CW + f8));
    }
  }
}

extern "C" void kernel_launch(void* const* d_in, const int* in_sizes, int n_in,
                              void* d_out, int out_size, void* d_ws, size_t ws_size,
                              hipStream_t stream) {
  const float* x  = (const float*)d_in[0];
  const int* ei   = (const int*)d_in[1];
  const float* W1 = (const float*)d_in[2];
  const float* b1 = (const float*)d_in[3];
  const float* W2 = (const float*)d_in[4];
  const float* b2 = (const float*)d_in[5];
  const float* pa = (const float*)d_in[6];

  const int N = in_sizes[0] / F;
  const int E = in_sizes[1] / 2;
  const int NR = N + 1;                              // +1 sentinel (zero) row per chunk
  const int NB = (N + BKT_NODES - 1) >> BKT_SHIFT;   // 391 for N=50000
  const int* src  = ei;
  const int* dstv = ei + E;

  // ws bump allocator
  char* p = (char*)d_ws;
  auto alloc = [&](size_t bytes) -> char* {
    char* r = p; p += (bytes + 255) & ~(size_t)255; return r;
  };
  int*   gcursor     = (int*)alloc(sizeof(int) * MAXNB);
  int*   row_start   = (int*)alloc(sizeof(int) * (size_t)N);
  int*   degv        = (int*)alloc(sizeof(int) * (size_t)N);
  float* dis         = (float*)alloc(sizeof(float) * (size_t)(N + 1));  // +1: dis[N]=0 sentinel
  float* rv          = (float*)alloc(sizeof(float) * (size_t)N);
  float* cv          = (float*)alloc(sizeof(float) * F);
  unsigned short* col = (unsigned short*)alloc(sizeof(short) * (size_t)NB * CAP);
  unsigned short* W1B  = (unsigned short*)alloc(sizeof(short) * F * F);
  unsigned short* W2T  = (unsigned short*)alloc(sizeof(short) * F * F);
  unsigned short* W12T = (unsigned short*)alloc(sizeof(short) * F * F);
  unsigned short* g   = (unsigned short*)alloc(sizeof(short) * (size_t)NR * F);
  unsigned short* t   = (unsigned short*)alloc(sizeof(short) * (size_t)NR * F);
  uint32_t* pairs = (uint32_t*)g;  // alias: pairs (9.6MB) dead before g is first written (gemm)

  hipMemsetAsync(gcursor, 0, sizeof(int) * MAXNB, stream);
  scatter_kernel<<<(E + CHUNK - 1) / CHUNK, 256, 0, stream>>>(src, dstv, gcursor, pairs, E, NB);
  build_kernel<<<NB, 256, 0, stream>>>(pairs, gcursor, row_start, degv, dis, col, N);
  // prep: W convert/transpose, cvec, sentinels, rsum (after build: pairs dead, dis ready)
  prep_kernel<<<769 + (N + 255) / 256, 256, 0, stream>>>(W1, W2, b1, W1B, W2T, cv, g, t, dis,
                                                         row_start, degv, col, rv, N, NR);
  // W12T[n][k] = (W1·W2)[k][n] = sum_m W2T[n][m] * W1[k][m]
  gemm_kernel<0, 1><<<2, 256, 0, stream>>>((const void*)W2T, W1B, nullptr, W12T, F, 0);

  // H = dis .* (bf16(x) @ W12), chunk-major   (g = S·H); A read exactly once (BN=256)
  gemm_kernel<1, 0><<<(N + 127) / 128, 256, 0, stream>>>((const void*)x, W12T, dis, g, N, NR);
  // t' = S·Â·H = d^2*(sum+self) over g
  aggregate_kernel<0><<<2048, 256, 0, stream>>>(g, dis, row_start, degv, col,
                                                nullptr, nullptr, nullptr, nullptr, t, N, NR);
  // out = S(A+I)·t' + r·(b1ᵀW2) + b2, PReLU -> fp32  ( = ÂÂH + r·c + b2 )
  aggregate_kernel<1><<<2048, 256, 0, stream>>>(t, dis, row_start, degv, col,
                                                b2, pa, rv, cv, d_out, N, NR);
}